// Round 12
// baseline (302.022 us; speedup 1.0000x reference)
//
#include <hip/hip_runtime.h>

#define BATCH 8
#define SDIM 2048
#define KDIM 2048
#define NDIM 2048

typedef __bf16 bf16_t;
typedef bf16_t bf16x4 __attribute__((ext_vector_type(4)));
typedef bf16_t bf16x8 __attribute__((ext_vector_type(8)));
typedef float f32x4 __attribute__((ext_vector_type(4)));
typedef float f32x8 __attribute__((ext_vector_type(8)));
typedef unsigned short u16x8 __attribute__((ext_vector_type(8)));

__device__ __forceinline__ void gl_lds16(const void* g, void* l) {
    // async global->LDS DMA, 16B/lane; LDS dest = wave-uniform base + lane*16
    __builtin_amdgcn_global_load_lds(
        (__attribute__((address_space(1))) void*)g,
        (__attribute__((address_space(3))) void*)l,
        16, 0, 0);
}

// ---------------- Pass 1a: A fp32 -> bf16 (elementwise) ----------------
__global__ __launch_bounds__(256)
void cvtA_kernel(const float* __restrict__ A, bf16_t* __restrict__ Abf) {
    const size_t total8 = (size_t)BATCH * SDIM * KDIM / 8;
    const size_t stride = (size_t)gridDim.x * 256;
    for (size_t i = (size_t)blockIdx.x * 256 + threadIdx.x; i < total8; i += stride) {
        f32x8 v = *reinterpret_cast<const f32x8*>(A + i * 8);
        *reinterpret_cast<bf16x8*>(Abf + i * 8) = __builtin_convertvector(v, bf16x8);
    }
}

// ------------- Pass 1b: B fp32 [K][N] -> bf16 B^T [N][K] ----------------
__global__ __launch_bounds__(256)
void cvtBT_kernel(const float* __restrict__ B, bf16_t* __restrict__ Bt) {
    __shared__ alignas(16) bf16_t T[64][72];
    const int gid = blockIdx.x;
    const int batch = gid & 7;
    const int tile = gid >> 3;
    const int k0g = (tile >> 5) * 64;
    const int n0g = (tile & 31) * 64;
    const float* Bb = B + (size_t)batch * KDIM * NDIM + (size_t)k0g * NDIM + n0g;
    bf16_t* Tb = Bt + (size_t)batch * NDIM * KDIM + (size_t)n0g * KDIM + k0g;

    const int t = threadIdx.x;
    const int kq = t & 15;
    const int nq = t >> 4;
    f32x4 v[4];
#pragma unroll
    for (int r = 0; r < 4; ++r)
        v[r] = *reinterpret_cast<const f32x4*>(Bb + (size_t)(kq * 4 + r) * NDIM + nq * 4);
#pragma unroll
    for (int j = 0; j < 4; ++j) {
        bf16x4 w = {(bf16_t)v[0][j], (bf16_t)v[1][j], (bf16_t)v[2][j], (bf16_t)v[3][j]};
        *reinterpret_cast<bf16x4*>(&T[nq * 4 + j][kq * 4]) = w;
    }
    __syncthreads();
    const int n = t >> 2, kc = t & 3;
    bf16x8 o0 = *reinterpret_cast<const bf16x8*>(&T[n][kc * 16]);
    bf16x8 o1 = *reinterpret_cast<const bf16x8*>(&T[n][kc * 16 + 8]);
    *reinterpret_cast<bf16x8*>(Tb + (size_t)n * KDIM + kc * 16) = o0;
    *reinterpret_cast<bf16x8*>(Tb + (size_t)n * KDIM + kc * 16 + 8) = o1;
}

// ---- Pass 2: 256x128 tile, 2 blocks/CU (16 waves/CU), counted vmcnt ----
// The R5-R11 invariant was 2 waves/SIMD in lockstep: LDS-read bursts and
// MFMA bursts serialize on their pipes (MfmaUtil pinned at ~33% across six
// schedules). Fix = TLP: acc 64 VGPR (per-wave 64x64), launch_bounds(512,4)
// => 4 waves/SIMD => 2 INDEPENDENT blocks/CU; block A's barrier/read stall
// is filled by block B's MFMA (m114 overlap), no compiler stagger needed.
// Per K-tile (BK=32) per wave: 3 gl_lds + 8 ds_read_b128 + 16 MFMA.
//   VM3; BAR          -- stage(j) landed everywhere (stage(j+1) in flight)
//   read 8 frags      -- plain HIP (compiler handles lgkm for MFMA)
//   LG0; BAR          -- own reads drained + all waves done reading buf P
//   STAGE(P, j+2)     -- WAR-safe overwrite; vmcnt never 0 until tail
//   MFMA x16          -- operands in regs
// LDS layout (R4-verified): per buffer A[16 rowGrp][4 kOct][16 rows][16B]
// then B[8 rowGrp][...]; DMA-linear (chunk==lane), frag reads 256B-contig.
#define VM3 asm volatile("s_waitcnt vmcnt(3)" ::: "memory")
#define VM0 asm volatile("s_waitcnt vmcnt(0)" ::: "memory")
#define LG0 asm volatile("s_waitcnt lgkmcnt(0)" ::: "memory")
#define BAR __builtin_amdgcn_s_barrier()
#define SB0 __builtin_amdgcn_sched_barrier(0)

__global__ __launch_bounds__(512, 4)
void bgemm_tlp(const bf16_t* __restrict__ A, const bf16_t* __restrict__ Bt,
               float* __restrict__ O) {
    __shared__ alignas(16) bf16_t lds[24576];   // 2 x 24KB = 48 KiB

    const int tid = threadIdx.x;
    const int gid = blockIdx.x;
    const int batch = gid & 7;          // one batch per XCD
    const int t = gid >> 3;             // 0..127
    const int bm = (t >> 4) * 256;
    const int bn = (t & 15) * 128;

    const int lane = tid & 63;
    const int wid = tid >> 6;           // 0..7
    const int wr = wid >> 1;            // 0..3 (64-row band)
    const int wc = wid & 1;             // 0..1 (64-col half)
    const int lr = lane & 15;
    const int lq = lane >> 4;

    const bf16_t* Ab = A + (size_t)batch * SDIM * KDIM;
    const bf16_t* Bb = Bt + (size_t)batch * NDIM * KDIM;
    float* Ob = O + (size_t)batch * SDIM * NDIM;

    // staging: wave w, inst I covers A rows I*128 + w*16 + lr (16 rows x 32k)
    const bf16_t* aStg = Ab + (size_t)(bm + wid * 16 + lr) * KDIM + lq * 8;
    const bf16_t* bStg = Bb + (size_t)(bn + wid * 16 + lr) * KDIM + lq * 8;

#define STAGE(BUF_, KT_) do { \
    gl_lds16(aStg + (size_t)(KT_) * 32,                      &lds[(BUF_) * 12288 + wid * 512]); \
    gl_lds16(aStg + 128 * (size_t)KDIM + (size_t)(KT_) * 32, &lds[(BUF_) * 12288 + 4096 + wid * 512]); \
    gl_lds16(bStg + (size_t)(KT_) * 32,                      &lds[(BUF_) * 12288 + 8192 + wid * 512]); \
} while (0)

    f32x4 acc[4][4];
#pragma unroll
    for (int m = 0; m < 4; ++m)
#pragma unroll
        for (int n = 0; n < 4; ++n)
            acc[m][n] = (f32x4){0.f, 0.f, 0.f, 0.f};

    const int rdA = lane * 8;           // + (wr*4+mf)*512 + buf*12288
    const int rdB = 8192 + lane * 8;    // + (wc*4+nf)*512 + buf*12288

#define TILE(P_, J_, DOSTAGE_, VM_) do { \
    VM_; \
    BAR; \
    SB0; \
    bf16x8 af_[4], bf_[4]; \
    _Pragma("unroll") \
    for (int mf_ = 0; mf_ < 4; ++mf_) \
        af_[mf_] = *reinterpret_cast<const bf16x8*>( \
            &lds[(P_) * 12288 + (wr * 4 + mf_) * 512 + rdA]); \
    _Pragma("unroll") \
    for (int nf_ = 0; nf_ < 4; ++nf_) \
        bf_[nf_] = *reinterpret_cast<const bf16x8*>( \
            &lds[(P_) * 12288 + (wc * 4 + nf_) * 512 + rdB]); \
    LG0; \
    SB0; \
    BAR; \
    if (DOSTAGE_) STAGE(P_, (J_) + 2); \
    __builtin_amdgcn_s_setprio(1); \
    _Pragma("unroll") \
    for (int mf_ = 0; mf_ < 4; ++mf_) \
        _Pragma("unroll") \
        for (int nf_ = 0; nf_ < 4; ++nf_) \
            acc[mf_][nf_] = __builtin_amdgcn_mfma_f32_16x16x32_bf16( \
                af_[mf_], bf_[nf_], acc[mf_][nf_], 0, 0, 0); \
    __builtin_amdgcn_s_setprio(0); \
} while (0)

    // prologue: stage tiles 0,1 (6 gl_lds in flight)
    STAGE(0, 0);
    STAGE(1, 1);

#pragma unroll 1
    for (int j = 0; j < 62; j += 2) {
        TILE(0, j, 1, VM3);
        TILE(1, j + 1, 1, VM3);
    }
    TILE(0, 62, 0, VM3);
    TILE(1, 63, 0, VM0);

    // epilogue: C/D layout col=lane&15, row=(lane>>4)*4+reg (R1-verified)
#pragma unroll
    for (int m = 0; m < 4; ++m) {
        const int row0 = bm + wr * 64 + m * 16 + lq * 4;
#pragma unroll
        for (int n = 0; n < 4; ++n) {
            const int col = bn + wc * 64 + n * 16 + lr;
#pragma unroll
            for (int j = 0; j < 4; ++j)
                Ob[(size_t)(row0 + j) * NDIM + col] = acc[m][n][j];
        }
    }
#undef TILE
#undef STAGE
}

// ---------------- Fallback: R1 fused kernel (proven) --------------------
__device__ __forceinline__ unsigned short f2bf(float f) {
    unsigned int u = __builtin_bit_cast(unsigned int, f);
    u += 0x7fffu + ((u >> 16) & 1u);
    return (unsigned short)(u >> 16);
}

__global__ __launch_bounds__(256, 2)
void bgemm_fused(const float* __restrict__ A, const float* __restrict__ B,
                 float* __restrict__ O) {
    __shared__ alignas(16) unsigned short Asl[2][4 * 128 * 8];
    __shared__ alignas(16) unsigned short Bsl[2][4 * 128 * 8];
    const int tid = threadIdx.x;
    const int gid = blockIdx.x;
    const int batch = gid & 7;
    const int t = gid >> 3;
    const int bm = (t >> 4) * 128;
    const int bn = (t & 15) * 128;
    const float* Ab = A + (size_t)batch * SDIM * KDIM;
    const float* Bb = B + (size_t)batch * KDIM * NDIM;
    float* Ob = O + (size_t)batch * SDIM * NDIM;
    const int lane = tid & 63;
    const int wid = tid >> 6;
    const int wr = wid >> 1, wc = wid & 1;
    const int lr = lane & 15, lq = lane >> 4;
    const int r0 = tid & 127, h0 = tid >> 7;
    u16x8 areg[2], breg[2];
    f32x4 acc[4][4];
#pragma unroll
    for (int m = 0; m < 4; ++m)
#pragma unroll
        for (int n = 0; n < 4; ++n) acc[m][n] = (f32x4){0.f, 0.f, 0.f, 0.f};
    auto stage_regs = [&](int kt) {
        const int k0 = kt * 32;
        const float* ap = Ab + (size_t)(bm + r0) * KDIM + k0 + h0 * 16;
        float4 a0 = *reinterpret_cast<const float4*>(ap + 0);
        float4 a1 = *reinterpret_cast<const float4*>(ap + 4);
        float4 a2 = *reinterpret_cast<const float4*>(ap + 8);
        float4 a3 = *reinterpret_cast<const float4*>(ap + 12);
        u16x8 u;
        u[0]=f2bf(a0.x);u[1]=f2bf(a0.y);u[2]=f2bf(a0.z);u[3]=f2bf(a0.w);
        u[4]=f2bf(a1.x);u[5]=f2bf(a1.y);u[6]=f2bf(a1.z);u[7]=f2bf(a1.w);
        areg[0]=u;
        u[0]=f2bf(a2.x);u[1]=f2bf(a2.y);u[2]=f2bf(a2.z);u[3]=f2bf(a2.w);
        u[4]=f2bf(a3.x);u[5]=f2bf(a3.y);u[6]=f2bf(a3.z);u[7]=f2bf(a3.w);
        areg[1]=u;
        const float* bp = Bb + (size_t)(k0 + h0 * 16) * NDIM + bn + r0;
        float f[16];
#pragma unroll
        for (int j = 0; j < 16; ++j) f[j] = bp[(size_t)j * NDIM];
        u16x8 v;
#pragma unroll
        for (int j = 0; j < 8; ++j) v[j] = f2bf(f[j]);
        breg[0] = v;
#pragma unroll
        for (int j = 0; j < 8; ++j) v[j] = f2bf(f[8 + j]);
        breg[1] = v;
    };
    auto regs_to_lds = [&](int b) {
#pragma unroll
        for (int o = 0; o < 2; ++o) {
            *reinterpret_cast<u16x8*>(&Asl[b][((h0*2+o)*128 + r0)*8]) = areg[o];
            *reinterpret_cast<u16x8*>(&Bsl[b][((h0*2+o)*128 + r0)*8]) = breg[o];
        }
    };
    stage_regs(0);
    regs_to_lds(0);
    int buf = 0;
    for (int kt = 0; kt < KDIM / 32; ++kt) {
        if (kt + 1 < KDIM / 32) stage_regs(kt + 1);
        __syncthreads();
        bf16x8 af[4], bfv[4];
#pragma unroll
        for (int m = 0; m < 4; ++m)
            af[m] = *reinterpret_cast<const bf16x8*>(&Asl[buf][(lq*128 + wr*64 + m*16 + lr)*8]);
#pragma unroll
        for (int n = 0; n < 4; ++n)
            bfv[n] = *reinterpret_cast<const bf16x8*>(&Bsl[buf][(lq*128 + wc*64 + n*16 + lr)*8]);
#pragma unroll
        for (int m = 0; m < 4; ++m)
#pragma unroll
            for (int n = 0; n < 4; ++n)
                acc[m][n] = __builtin_amdgcn_mfma_f32_16x16x32_bf16(af[m], bfv[n], acc[m][n], 0, 0, 0);
        if (kt + 1 < KDIM / 32) regs_to_lds(buf ^ 1);
        buf ^= 1;
    }
#pragma unroll
    for (int m = 0; m < 4; ++m) {
        const int row0 = bm + wr * 64 + m * 16 + lq * 4;
#pragma unroll
        for (int n = 0; n < 4; ++n) {
            const int col = bn + wc * 64 + n * 16 + lr;
#pragma unroll
            for (int j = 0; j < 4; ++j)
                Ob[(size_t)(row0 + j) * NDIM + col] = acc[m][n][j];
        }
    }
}

extern "C" void kernel_launch(void* const* d_in, const int* in_sizes, int n_in,
                              void* d_out, int out_size, void* d_ws, size_t ws_size,
                              hipStream_t stream) {
    const float* a = (const float*)d_in[0];
    const float* b = (const float*)d_in[1];
    float* o = (float*)d_out;
    const size_t half = (size_t)BATCH * SDIM * KDIM * sizeof(bf16_t);  // 64 MiB
    if (ws_size >= 2 * half) {
        bf16_t* Abf = (bf16_t*)d_ws;
        bf16_t* Bt = (bf16_t*)((char*)d_ws + half);
        hipLaunchKernelGGL(cvtA_kernel, dim3(4096), dim3(256), 0, stream, a, Abf);
        hipLaunchKernelGGL(cvtBT_kernel, dim3(8192), dim3(256), 0, stream, b, Bt);
        // 8 batches x (2048/256) x (2048/128) = 1024 blocks
        hipLaunchKernelGGL(bgemm_tlp, dim3(1024), dim3(512), 0, stream, Abf, Bt, o);
    } else {
        hipLaunchKernelGGL(bgemm_fused, dim3(2048), dim3(256), 0, stream, a, b, o);
    }
}

// Round 13
// 257.136 us; speedup vs baseline: 1.1746x; 1.1746x over previous
//
#include <hip/hip_runtime.h>

#define BATCH 8
#define SDIM 2048
#define KDIM 2048
#define NDIM 2048

typedef __bf16 bf16_t;
typedef bf16_t bf16x4 __attribute__((ext_vector_type(4)));
typedef bf16_t bf16x8 __attribute__((ext_vector_type(8)));
typedef float f32x4 __attribute__((ext_vector_type(4)));
typedef float f32x8 __attribute__((ext_vector_type(8)));
typedef unsigned short u16x8 __attribute__((ext_vector_type(8)));

__device__ __forceinline__ void gl_lds16(const void* g, void* l) {
    // async global->LDS DMA, 16B/lane; LDS dest = wave-uniform base + lane*16
    __builtin_amdgcn_global_load_lds(
        (__attribute__((address_space(1))) void*)g,
        (__attribute__((address_space(3))) void*)l,
        16, 0, 0);
}

// ---------------- Pass 1a: A fp32 -> bf16 (elementwise) ----------------
__global__ __launch_bounds__(256)
void cvtA_kernel(const float* __restrict__ A, bf16_t* __restrict__ Abf) {
    const size_t total8 = (size_t)BATCH * SDIM * KDIM / 8;
    const size_t stride = (size_t)gridDim.x * 256;
    for (size_t i = (size_t)blockIdx.x * 256 + threadIdx.x; i < total8; i += stride) {
        f32x8 v = *reinterpret_cast<const f32x8*>(A + i * 8);
        *reinterpret_cast<bf16x8*>(Abf + i * 8) = __builtin_convertvector(v, bf16x8);
    }
}

// ------------- Pass 1b: B fp32 [K][N] -> bf16 B^T [N][K] ----------------
__global__ __launch_bounds__(256)
void cvtBT_kernel(const float* __restrict__ B, bf16_t* __restrict__ Bt) {
    __shared__ alignas(16) bf16_t T[64][72];
    const int gid = blockIdx.x;
    const int batch = gid & 7;
    const int tile = gid >> 3;
    const int k0g = (tile >> 5) * 64;
    const int n0g = (tile & 31) * 64;
    const float* Bb = B + (size_t)batch * KDIM * NDIM + (size_t)k0g * NDIM + n0g;
    bf16_t* Tb = Bt + (size_t)batch * NDIM * KDIM + (size_t)n0g * KDIM + k0g;

    const int t = threadIdx.x;
    const int kq = t & 15;
    const int nq = t >> 4;
    f32x4 v[4];
#pragma unroll
    for (int r = 0; r < 4; ++r)
        v[r] = *reinterpret_cast<const f32x4*>(Bb + (size_t)(kq * 4 + r) * NDIM + nq * 4);
#pragma unroll
    for (int j = 0; j < 4; ++j) {
        bf16x4 w = {(bf16_t)v[0][j], (bf16_t)v[1][j], (bf16_t)v[2][j], (bf16_t)v[3][j]};
        *reinterpret_cast<bf16x4*>(&T[nq * 4 + j][kq * 4]) = w;
    }
    __syncthreads();
    const int n = t >> 2, kc = t & 3;
    bf16x8 o0 = *reinterpret_cast<const bf16x8*>(&T[n][kc * 16]);
    bf16x8 o1 = *reinterpret_cast<const bf16x8*>(&T[n][kc * 16 + 8]);
    *reinterpret_cast<bf16x8*>(Tb + (size_t)n * KDIM + kc * 16) = o0;
    *reinterpret_cast<bf16x8*>(Tb + (size_t)n * KDIM + kc * 16 + 8) = o1;
}

// ------ Pass 2: 256x256 ring GEMM, ZERO scheduler fences in region ------
// Identical to the R8 ring (1 barrier/K-tile, 4-deep buffer ring, counted
// vmcnt: youngest-waited stage issued 3 regions (~10k cyc) earlier) with
// the s_setprio pair REMOVED. Theory: s_setprio (unmodeled side effects)
// was a scheduler fence in ALL R5-R12 variants, forcing [read burst][MFMA
// burst] serialization (LDS pipe then MFMA pipe, ~3340 cyc/K-tile). With
// no fences, hipcc interleaves ds_read<->MFMA with fine-grained lgkmcnt
// (m97-dump behavior): LDS pipe (~2300 cyc/CU) and MFMA pipe (~2480/SIMD)
// overlap. WAR safety: each wave's reads of buf b are fully returned
// before its last MFMA of region b issues (compiler-inserted lgkm waits,
// in-order DS returns), so the next barrier certifies "reads done" before
// STAGE overwrites. vmcnt never drains to 0 until the 3-region tail.
#define VM8 asm volatile("s_waitcnt vmcnt(8)" ::: "memory")
#define VM4 asm volatile("s_waitcnt vmcnt(4)" ::: "memory")
#define VM0 asm volatile("s_waitcnt vmcnt(0)" ::: "memory")
#define NOOP ((void)0)

__global__ __launch_bounds__(512, 2)
void bgemm_free(const bf16_t* __restrict__ A, const bf16_t* __restrict__ Bt,
                float* __restrict__ O) {
    __shared__ alignas(16) bf16_t lds[65536];   // 4 x 32KB = 128 KiB

    const int tid = threadIdx.x;
    const int gid = blockIdx.x;
    const int batch = gid & 7;          // one batch per XCD
    const int t = gid >> 3;
    const int bm = (t >> 3) * 256;
    const int bn = (t & 7) * 256;

    const int lane = tid & 63;
    const int wid = tid >> 6;           // 0..7
    const int wr = wid >> 2;            // 0..1 (128-row half)
    const int wc = wid & 3;             // 0..3 (64-col quarter)
    const int lr = lane & 15;
    const int lq = lane >> 4;

    const bf16_t* Ab = A + (size_t)batch * SDIM * KDIM;
    const bf16_t* Bb = Bt + (size_t)batch * NDIM * KDIM;
    float* Ob = O + (size_t)batch * SDIM * NDIM;

    // staging sources: wave w covers rows w*32..w*32+31 (2 insts of 16 rows)
    const bf16_t* aSrc0 = Ab + (size_t)(bm + wid * 32 + lr) * KDIM + lq * 8;
    const bf16_t* aSrc1 = aSrc0 + (size_t)16 * KDIM;
    const bf16_t* bSrc0 = Bb + (size_t)(bn + wid * 32 + lr) * KDIM + lq * 8;
    const bf16_t* bSrc1 = bSrc0 + (size_t)16 * KDIM;

    const int aDst0 = (wid * 2) * 512;       // LDS elem offset of rowOct 2w
    const int aDst1 = (wid * 2 + 1) * 512;
    const int rdA = lq * 128 + lr * 8;       // + (wr*8+m)*512 + buf*16384
    const int rdB = 8192 + lq * 128 + lr * 8;

#define STAGE(BUF_, KT_) do { \
    gl_lds16(aSrc0 + (size_t)(KT_) * 32, &lds[(BUF_) * 16384 + aDst0]); \
    gl_lds16(aSrc1 + (size_t)(KT_) * 32, &lds[(BUF_) * 16384 + aDst1]); \
    gl_lds16(bSrc0 + (size_t)(KT_) * 32, &lds[(BUF_) * 16384 + 8192 + aDst0]); \
    gl_lds16(bSrc1 + (size_t)(KT_) * 32, &lds[(BUF_) * 16384 + 8192 + aDst1]); \
} while (0)

    f32x4 acc[8][4];
#pragma unroll
    for (int m = 0; m < 8; ++m)
#pragma unroll
        for (int n = 0; n < 4; ++n)
            acc[m][n] = (f32x4){0.f, 0.f, 0.f, 0.f};

// Region: wait own stage(j) landed -> barrier (cross-wave: stage(j) done,
// all reads of buf (j-1)&3 done) -> issue stage(j+3) -> reads+MFMA free-form.
#define BODY(BUF_, STAGE_STMT, VM_STMT) do { \
    VM_STMT; \
    __builtin_amdgcn_s_barrier(); \
    STAGE_STMT; \
    bf16x8 af_[8], bf_[4]; \
    _Pragma("unroll") \
    for (int m_ = 0; m_ < 8; ++m_) \
        af_[m_] = *reinterpret_cast<const bf16x8*>( \
            &lds[(BUF_) * 16384 + (wr * 8 + m_) * 512 + rdA]); \
    _Pragma("unroll") \
    for (int n_ = 0; n_ < 4; ++n_) \
        bf_[n_] = *reinterpret_cast<const bf16x8*>( \
            &lds[(BUF_) * 16384 + (wc * 4 + n_) * 512 + rdB]); \
    _Pragma("unroll") \
    for (int m_ = 0; m_ < 8; ++m_) \
        _Pragma("unroll") \
        for (int n_ = 0; n_ < 4; ++n_) \
            acc[m_][n_] = __builtin_amdgcn_mfma_f32_16x16x32_bf16( \
                af_[m_], bf_[n_], acc[m_][n_], 0, 0, 0); \
} while (0)

    // prologue: stages for KT 0,1,2 in flight (12 loads)
    STAGE(0, 0);
    STAGE(1, 1);
    STAGE(2, 2);

#pragma unroll 1
    for (int j4 = 0; j4 < 60; j4 += 4) {      // j = 0..59, stages 3..62
        BODY(0, STAGE(3, j4 + 3), VM8);
        BODY(1, STAGE(0, j4 + 4), VM8);
        BODY(2, STAGE(1, j4 + 5), VM8);
        BODY(3, STAGE(2, j4 + 6), VM8);
    }
    BODY(0, STAGE(3, 63), VM8);               // j=60
    BODY(1, NOOP, VM8);                       // j=61
    BODY(2, NOOP, VM4);                       // j=62
    BODY(3, NOOP, VM0);                       // j=63

    // epilogue: C/D layout col=lane&15, row=(lane>>4)*4+reg (R1-verified)
#pragma unroll
    for (int m = 0; m < 8; ++m) {
        const int row0 = bm + wr * 128 + m * 16 + lq * 4;
#pragma unroll
        for (int n = 0; n < 4; ++n) {
            const int col = bn + wc * 64 + n * 16 + lr;
#pragma unroll
            for (int j = 0; j < 4; ++j)
                Ob[(size_t)(row0 + j) * NDIM + col] = acc[m][n][j];
        }
    }
#undef BODY
#undef STAGE
}

// ---------------- Fallback: R1 fused kernel (proven) --------------------
__device__ __forceinline__ unsigned short f2bf(float f) {
    unsigned int u = __builtin_bit_cast(unsigned int, f);
    u += 0x7fffu + ((u >> 16) & 1u);
    return (unsigned short)(u >> 16);
}

__global__ __launch_bounds__(256, 2)
void bgemm_fused(const float* __restrict__ A, const float* __restrict__ B,
                 float* __restrict__ O) {
    __shared__ alignas(16) unsigned short Asl[2][4 * 128 * 8];
    __shared__ alignas(16) unsigned short Bsl[2][4 * 128 * 8];
    const int tid = threadIdx.x;
    const int gid = blockIdx.x;
    const int batch = gid & 7;
    const int t = gid >> 3;
    const int bm = (t >> 4) * 128;
    const int bn = (t & 15) * 128;
    const float* Ab = A + (size_t)batch * SDIM * KDIM;
    const float* Bb = B + (size_t)batch * KDIM * NDIM;
    float* Ob = O + (size_t)batch * SDIM * NDIM;
    const int lane = tid & 63;
    const int wid = tid >> 6;
    const int wr = wid >> 1, wc = wid & 1;
    const int lr = lane & 15, lq = lane >> 4;
    const int r0 = tid & 127, h0 = tid >> 7;
    u16x8 areg[2], breg[2];
    f32x4 acc[4][4];
#pragma unroll
    for (int m = 0; m < 4; ++m)
#pragma unroll
        for (int n = 0; n < 4; ++n) acc[m][n] = (f32x4){0.f, 0.f, 0.f, 0.f};
    auto stage_regs = [&](int kt) {
        const int k0 = kt * 32;
        const float* ap = Ab + (size_t)(bm + r0) * KDIM + k0 + h0 * 16;
        float4 a0 = *reinterpret_cast<const float4*>(ap + 0);
        float4 a1 = *reinterpret_cast<const float4*>(ap + 4);
        float4 a2 = *reinterpret_cast<const float4*>(ap + 8);
        float4 a3 = *reinterpret_cast<const float4*>(ap + 12);
        u16x8 u;
        u[0]=f2bf(a0.x);u[1]=f2bf(a0.y);u[2]=f2bf(a0.z);u[3]=f2bf(a0.w);
        u[4]=f2bf(a1.x);u[5]=f2bf(a1.y);u[6]=f2bf(a1.z);u[7]=f2bf(a1.w);
        areg[0]=u;
        u[0]=f2bf(a2.x);u[1]=f2bf(a2.y);u[2]=f2bf(a2.z);u[3]=f2bf(a2.w);
        u[4]=f2bf(a3.x);u[5]=f2bf(a3.y);u[6]=f2bf(a3.z);u[7]=f2bf(a3.w);
        areg[1]=u;
        const float* bp = Bb + (size_t)(k0 + h0 * 16) * NDIM + bn + r0;
        float f[16];
#pragma unroll
        for (int j = 0; j < 16; ++j) f[j] = bp[(size_t)j * NDIM];
        u16x8 v;
#pragma unroll
        for (int j = 0; j < 8; ++j) v[j] = f2bf(f[j]);
        breg[0] = v;
#pragma unroll
        for (int j = 0; j < 8; ++j) v[j] = f2bf(f[8 + j]);
        breg[1] = v;
    };
    auto regs_to_lds = [&](int b) {
#pragma unroll
        for (int o = 0; o < 2; ++o) {
            *reinterpret_cast<u16x8*>(&Asl[b][((h0*2+o)*128 + r0)*8]) = areg[o];
            *reinterpret_cast<u16x8*>(&Bsl[b][((h0*2+o)*128 + r0)*8]) = breg[o];
        }
    };
    stage_regs(0);
    regs_to_lds(0);
    int buf = 0;
    for (int kt = 0; kt < KDIM / 32; ++kt) {
        if (kt + 1 < KDIM / 32) stage_regs(kt + 1);
        __syncthreads();
        bf16x8 af[4], bfv[4];
#pragma unroll
        for (int m = 0; m < 4; ++m)
            af[m] = *reinterpret_cast<const bf16x8*>(&Asl[buf][(lq*128 + wr*64 + m*16 + lr)*8]);
#pragma unroll
        for (int n = 0; n < 4; ++n)
            bfv[n] = *reinterpret_cast<const bf16x8*>(&Bsl[buf][(lq*128 + wc*64 + n*16 + lr)*8]);
#pragma unroll
        for (int m = 0; m < 4; ++m)
#pragma unroll
            for (int n = 0; n < 4; ++n)
                acc[m][n] = __builtin_amdgcn_mfma_f32_16x16x32_bf16(af[m], bfv[n], acc[m][n], 0, 0, 0);
        if (kt + 1 < KDIM / 32) regs_to_lds(buf ^ 1);
        buf ^= 1;
    }
#pragma unroll
    for (int m = 0; m < 4; ++m) {
        const int row0 = bm + wr * 64 + m * 16 + lq * 4;
#pragma unroll
        for (int n = 0; n < 4; ++n) {
            const int col = bn + wc * 64 + n * 16 + lr;
#pragma unroll
            for (int j = 0; j < 4; ++j)
                Ob[(size_t)(row0 + j) * NDIM + col] = acc[m][n][j];
        }
    }
}

extern "C" void kernel_launch(void* const* d_in, const int* in_sizes, int n_in,
                              void* d_out, int out_size, void* d_ws, size_t ws_size,
                              hipStream_t stream) {
    const float* a = (const float*)d_in[0];
    const float* b = (const float*)d_in[1];
    float* o = (float*)d_out;
    const size_t half = (size_t)BATCH * SDIM * KDIM * sizeof(bf16_t);  // 64 MiB
    if (ws_size >= 2 * half) {
        bf16_t* Abf = (bf16_t*)d_ws;
        bf16_t* Bt = (bf16_t*)((char*)d_ws + half);
        hipLaunchKernelGGL(cvtA_kernel, dim3(4096), dim3(256), 0, stream, a, Abf);
        hipLaunchKernelGGL(cvtBT_kernel, dim3(8192), dim3(256), 0, stream, b, Bt);
        hipLaunchKernelGGL(bgemm_free, dim3(512), dim3(512), 0, stream, Abf, Bt, o);
    } else {
        hipLaunchKernelGGL(bgemm_fused, dim3(2048), dim3(256), 0, stream, a, b, o);
    }
}

// Round 14
// 251.860 us; speedup vs baseline: 1.1992x; 1.0210x over previous
//
#include <hip/hip_runtime.h>

#define BATCH 8
#define SDIM 2048
#define KDIM 2048
#define NDIM 2048

typedef __bf16 bf16_t;
typedef bf16_t bf16x4 __attribute__((ext_vector_type(4)));
typedef bf16_t bf16x8 __attribute__((ext_vector_type(8)));
typedef float f32x4 __attribute__((ext_vector_type(4)));
typedef float f32x8 __attribute__((ext_vector_type(8)));
typedef unsigned short u16x8 __attribute__((ext_vector_type(8)));

__device__ __forceinline__ void gl_lds16(const void* g, void* l) {
    // async global->LDS DMA, 16B/lane; LDS dest = wave-uniform base + lane*16
    __builtin_amdgcn_global_load_lds(
        (__attribute__((address_space(1))) void*)g,
        (__attribute__((address_space(3))) void*)l,
        16, 0, 0);
}

// ---------------- Pass 1a: A fp32 -> bf16 (elementwise) ----------------
__global__ __launch_bounds__(256)
void cvtA_kernel(const float* __restrict__ A, bf16_t* __restrict__ Abf) {
    const size_t total8 = (size_t)BATCH * SDIM * KDIM / 8;
    const size_t stride = (size_t)gridDim.x * 256;
    for (size_t i = (size_t)blockIdx.x * 256 + threadIdx.x; i < total8; i += stride) {
        f32x8 v = *reinterpret_cast<const f32x8*>(A + i * 8);
        *reinterpret_cast<bf16x8*>(Abf + i * 8) = __builtin_convertvector(v, bf16x8);
    }
}

// ------------- Pass 1b: B fp32 [K][N] -> bf16 B^T [N][K] ----------------
__global__ __launch_bounds__(256)
void cvtBT_kernel(const float* __restrict__ B, bf16_t* __restrict__ Bt) {
    __shared__ alignas(16) bf16_t T[64][72];
    const int gid = blockIdx.x;
    const int batch = gid & 7;
    const int tile = gid >> 3;
    const int k0g = (tile >> 5) * 64;
    const int n0g = (tile & 31) * 64;
    const float* Bb = B + (size_t)batch * KDIM * NDIM + (size_t)k0g * NDIM + n0g;
    bf16_t* Tb = Bt + (size_t)batch * NDIM * KDIM + (size_t)n0g * KDIM + k0g;

    const int t = threadIdx.x;
    const int kq = t & 15;
    const int nq = t >> 4;
    f32x4 v[4];
#pragma unroll
    for (int r = 0; r < 4; ++r)
        v[r] = *reinterpret_cast<const f32x4*>(Bb + (size_t)(kq * 4 + r) * NDIM + nq * 4);
#pragma unroll
    for (int j = 0; j < 4; ++j) {
        bf16x4 w = {(bf16_t)v[0][j], (bf16_t)v[1][j], (bf16_t)v[2][j], (bf16_t)v[3][j]};
        *reinterpret_cast<bf16x4*>(&T[nq * 4 + j][kq * 4]) = w;
    }
    __syncthreads();
    const int n = t >> 2, kc = t & 3;
    bf16x8 o0 = *reinterpret_cast<const bf16x8*>(&T[n][kc * 16]);
    bf16x8 o1 = *reinterpret_cast<const bf16x8*>(&T[n][kc * 16 + 8]);
    *reinterpret_cast<bf16x8*>(Tb + (size_t)n * KDIM + kc * 16) = o0;
    *reinterpret_cast<bf16x8*>(Tb + (size_t)n * KDIM + kc * 16 + 8) = o1;
}

// -------- Pass 2: m201 template, NO sched_barrier order-pinning ---------
// Identical skeleton to R11 (256x256, BK=64, 2 LDS buffers, 4 quadrant
// phases/K-tile, counted vmcnt(2) once per K-tile) with ALL sched_barriers
// removed EXCEPT the rule-18 one right after each lgkmcnt(0) (prevents
// MFMA hoisting above its operand drain - a correctness fence). R11's 5
// SB0s/phase were the m141 anti-pattern (order-pinning = 510 TF); m201
// itself (1563 TF, 62% MfmaUtil, same geometry) has none. With the
// scheduler free, reads/stages migrate into MFMA shadows across phase
// boundaries (the compiler's m97-dump behavior) while the {reads -> BAR ->
// lgkm0 -> MFMA -> BAR} skeleton keeps the data-race discipline intact.
#define VM2 asm volatile("s_waitcnt vmcnt(2)" ::: "memory")
#define VM0 asm volatile("s_waitcnt vmcnt(0)" ::: "memory")
#define BAR __builtin_amdgcn_s_barrier()
#define LG0 do { asm volatile("s_waitcnt lgkmcnt(0)" ::: "memory"); \
                 __builtin_amdgcn_sched_barrier(0); } while (0)
#define NOOP ((void)0)

__global__ __launch_bounds__(512, 2)
void bgemm_m201(const bf16_t* __restrict__ A, const bf16_t* __restrict__ Bt,
                float* __restrict__ O) {
    __shared__ alignas(16) bf16_t lds[65536];   // 2 x 64KB = 128 KiB

    const int tid = threadIdx.x;
    const int gid = blockIdx.x;
    const int batch = gid & 7;          // one batch per XCD
    const int t = gid >> 3;
    const int bm = (t >> 3) * 256;
    const int bn = (t & 7) * 256;

    const int lane = tid & 63;
    const int wid = tid >> 6;           // 0..7
    const int wr = wid >> 2;            // 0..1 (128-row half)
    const int wc = wid & 3;             // 0..3 (64-col quarter)
    const int lr = lane & 15;
    const int lq = lane >> 4;

    const bf16_t* Ab = A + (size_t)batch * SDIM * KDIM;
    const bf16_t* Bb = Bt + (size_t)batch * NDIM * KDIM;
    float* Ob = O + (size_t)batch * SDIM * NDIM;

    // staging source per thread: inst i covers tile rows 64i..64i+63
    const bf16_t* aStg = Ab + (size_t)(bm + ((tid >> 7) << 4) + (tid & 15)) * KDIM
                            + ((tid >> 4) & 7) * 8;
    const bf16_t* bStg = Bb + (size_t)(bn + ((tid >> 7) << 4) + (tid & 15)) * KDIM
                            + ((tid >> 4) & 7) * 8;

// stage inst: A inst I into buf PD at K-tile KT (B same + 16384 elems)
#define STG_A(PD_, I_, KT_) gl_lds16(aStg + (size_t)(I_) * 64 * KDIM + (size_t)(KT_) * 64, \
                                     &lds[(PD_) * 32768 + (I_) * 4096 + wid * 512])
#define STG_B(PD_, I_, KT_) gl_lds16(bStg + (size_t)(I_) * 64 * KDIM + (size_t)(KT_) * 64, \
                                     &lds[(PD_) * 32768 + 16384 + (I_) * 4096 + wid * 512])

    f32x4 acc[8][4];
#pragma unroll
    for (int m = 0; m < 8; ++m)
#pragma unroll
        for (int n = 0; n < 4; ++n)
            acc[m][n] = (f32x4){0.f, 0.f, 0.f, 0.f};

    // fragment registers: A half (4m x 2ks), B halves (2n x 2ks each)
    bf16x8 afr[4][2], b0f[2][2], b1f[2][2];

#define RD_A(P_, MH_) do { \
    _Pragma("unroll") \
    for (int mq_ = 0; mq_ < 4; ++mq_) \
        _Pragma("unroll") \
        for (int ks_ = 0; ks_ < 2; ++ks_) \
            afr[mq_][ks_] = *reinterpret_cast<const bf16x8*>( \
                &lds[(P_) * 32768 + ((wr * 8 + (MH_) * 4 + mq_) * 128 \
                                     + (ks_ * 4 + lq) * 16 + lr) * 8]); \
} while (0)

#define RD_B(P_, NH_, BF_) do { \
    _Pragma("unroll") \
    for (int nq_ = 0; nq_ < 2; ++nq_) \
        _Pragma("unroll") \
        for (int ks_ = 0; ks_ < 2; ++ks_) \
            BF_[nq_][ks_] = *reinterpret_cast<const bf16x8*>( \
                &lds[(P_) * 32768 + 16384 + ((wc * 4 + (NH_) * 2 + nq_) * 128 \
                                             + (ks_ * 4 + lq) * 16 + lr) * 8]); \
} while (0)

#define MFMA_Q(MB_, NB_, BF_) do { \
    __builtin_amdgcn_s_setprio(1); \
    _Pragma("unroll") \
    for (int mq_ = 0; mq_ < 4; ++mq_) \
        _Pragma("unroll") \
        for (int nq_ = 0; nq_ < 2; ++nq_) \
            _Pragma("unroll") \
            for (int ks_ = 0; ks_ < 2; ++ks_) \
                acc[(MB_) + mq_][(NB_) + nq_] = __builtin_amdgcn_mfma_f32_16x16x32_bf16( \
                    afr[mq_][ks_], BF_[nq_][ks_], acc[(MB_) + mq_][(NB_) + nq_], 0, 0, 0); \
    __builtin_amdgcn_s_setprio(0); \
} while (0)

// BODY computes tile in buf P_; S1_-S3_ stage pairs1-3 of next tile,
// S0N_ stages pair0 of tile-after-next, VM_ is the once-per-tile vmcnt.
// Only scheduling fence: the rule-18 SB0 inside LG0.
#define BODY(P_, S1_, S2_, S3_, S0N_, VM_) do { \
    /* ph0 */ RD_A(P_, 0); RD_B(P_, 0, b0f); S1_; BAR; LG0; \
              MFMA_Q(0, 0, b0f); BAR; \
    /* ph1 */ RD_B(P_, 1, b1f); S2_; BAR; LG0; \
              MFMA_Q(0, 2, b1f); BAR; \
    /* ph2 */ RD_A(P_, 1); S3_; BAR; LG0; \
              MFMA_Q(4, 2, b1f); BAR; \
    /* ph3 */ S0N_; VM_; BAR; \
              MFMA_Q(4, 0, b0f); BAR; \
} while (0)

    // prologue: all 8 loads of tile0 -> buf0; pair0 of tile1 -> buf1
    STG_A(0, 0, 0); STG_A(0, 1, 0); STG_A(0, 2, 0); STG_A(0, 3, 0);
    STG_B(0, 0, 0); STG_B(0, 1, 0); STG_B(0, 2, 0); STG_B(0, 3, 0);
    STG_A(1, 0, 1); STG_A(1, 1, 1);
    VM2;                                 // tile0 landed; pair0(t1) in flight
    BAR;

#pragma unroll 1
    for (int j = 0; j < 30; j += 2) {    // tiles j (buf0) and j+1 (buf1)
        BODY(0,
             (STG_A(1, 2, j + 1), STG_A(1, 3, j + 1)),
             (STG_B(1, 0, j + 1), STG_B(1, 1, j + 1)),
             (STG_B(1, 2, j + 1), STG_B(1, 3, j + 1)),
             (STG_A(0, 0, j + 2), STG_A(0, 1, j + 2)), VM2);
        BODY(1,
             (STG_A(0, 2, j + 2), STG_A(0, 3, j + 2)),
             (STG_B(0, 0, j + 2), STG_B(0, 1, j + 2)),
             (STG_B(0, 2, j + 2), STG_B(0, 3, j + 2)),
             (STG_A(1, 0, j + 3), STG_A(1, 1, j + 3)), VM2);
    }
    // tile 30: stage pairs1-3 of t31; no further pair0; drain fully
    BODY(0,
         (STG_A(1, 2, 31), STG_A(1, 3, 31)),
         (STG_B(1, 0, 31), STG_B(1, 1, 31)),
         (STG_B(1, 2, 31), STG_B(1, 3, 31)),
         NOOP, VM0);
    // tile 31: pure compute
    BODY(1, NOOP, NOOP, NOOP, NOOP, NOOP);

    // epilogue: C/D layout col=lane&15, row=(lane>>4)*4+reg (R1-verified)
#pragma unroll
    for (int m = 0; m < 8; ++m) {
        const int row0 = bm + wr * 128 + m * 16 + lq * 4;
#pragma unroll
        for (int n = 0; n < 4; ++n) {
            const int col = bn + wc * 64 + n * 16 + lr;
#pragma unroll
            for (int j = 0; j < 4; ++j)
                Ob[(size_t)(row0 + j) * NDIM + col] = acc[m][n][j];
        }
    }
#undef BODY
#undef MFMA_Q
#undef RD_B
#undef RD_A
#undef STG_B
#undef STG_A
}

// ---------------- Fallback: R1 fused kernel (proven) --------------------
__device__ __forceinline__ unsigned short f2bf(float f) {
    unsigned int u = __builtin_bit_cast(unsigned int, f);
    u += 0x7fffu + ((u >> 16) & 1u);
    return (unsigned short)(u >> 16);
}

__global__ __launch_bounds__(256, 2)
void bgemm_fused(const float* __restrict__ A, const float* __restrict__ B,
                 float* __restrict__ O) {
    __shared__ alignas(16) unsigned short Asl[2][4 * 128 * 8];
    __shared__ alignas(16) unsigned short Bsl[2][4 * 128 * 8];
    const int tid = threadIdx.x;
    const int gid = blockIdx.x;
    const int batch = gid & 7;
    const int t = gid >> 3;
    const int bm = (t >> 4) * 128;
    const int bn = (t & 15) * 128;
    const float* Ab = A + (size_t)batch * SDIM * KDIM;
    const float* Bb = B + (size_t)batch * KDIM * NDIM;
    float* Ob = O + (size_t)batch * SDIM * NDIM;
    const int lane = tid & 63;
    const int wid = tid >> 6;
    const int wr = wid >> 1, wc = wid & 1;
    const int lr = lane & 15, lq = lane >> 4;
    const int r0 = tid & 127, h0 = tid >> 7;
    u16x8 areg[2], breg[2];
    f32x4 acc[4][4];
#pragma unroll
    for (int m = 0; m < 4; ++m)
#pragma unroll
        for (int n = 0; n < 4; ++n) acc[m][n] = (f32x4){0.f, 0.f, 0.f, 0.f};
    auto stage_regs = [&](int kt) {
        const int k0 = kt * 32;
        const float* ap = Ab + (size_t)(bm + r0) * KDIM + k0 + h0 * 16;
        float4 a0 = *reinterpret_cast<const float4*>(ap + 0);
        float4 a1 = *reinterpret_cast<const float4*>(ap + 4);
        float4 a2 = *reinterpret_cast<const float4*>(ap + 8);
        float4 a3 = *reinterpret_cast<const float4*>(ap + 12);
        u16x8 u;
        u[0]=f2bf(a0.x);u[1]=f2bf(a0.y);u[2]=f2bf(a0.z);u[3]=f2bf(a0.w);
        u[4]=f2bf(a1.x);u[5]=f2bf(a1.y);u[6]=f2bf(a1.z);u[7]=f2bf(a1.w);
        areg[0]=u;
        u[0]=f2bf(a2.x);u[1]=f2bf(a2.y);u[2]=f2bf(a2.z);u[3]=f2bf(a2.w);
        u[4]=f2bf(a3.x);u[5]=f2bf(a3.y);u[6]=f2bf(a3.z);u[7]=f2bf(a3.w);
        areg[1]=u;
        const float* bp = Bb + (size_t)(k0 + h0 * 16) * NDIM + bn + r0;
        float f[16];
#pragma unroll
        for (int j = 0; j < 16; ++j) f[j] = bp[(size_t)j * NDIM];
        u16x8 v;
#pragma unroll
        for (int j = 0; j < 8; ++j) v[j] = f2bf(f[j]);
        breg[0] = v;
#pragma unroll
        for (int j = 0; j < 8; ++j) v[j] = f2bf(f[8 + j]);
        breg[1] = v;
    };
    auto regs_to_lds = [&](int b) {
#pragma unroll
        for (int o = 0; o < 2; ++o) {
            *reinterpret_cast<u16x8*>(&Asl[b][((h0*2+o)*128 + r0)*8]) = areg[o];
            *reinterpret_cast<u16x8*>(&Bsl[b][((h0*2+o)*128 + r0)*8]) = breg[o];
        }
    };
    stage_regs(0);
    regs_to_lds(0);
    int buf = 0;
    for (int kt = 0; kt < KDIM / 32; ++kt) {
        if (kt + 1 < KDIM / 32) stage_regs(kt + 1);
        __syncthreads();
        bf16x8 af[4], bfv[4];
#pragma unroll
        for (int m = 0; m < 4; ++m)
            af[m] = *reinterpret_cast<const bf16x8*>(&Asl[buf][(lq*128 + wr*64 + m*16 + lr)*8]);
#pragma unroll
        for (int n = 0; n < 4; ++n)
            bfv[n] = *reinterpret_cast<const bf16x8*>(&Bsl[buf][(lq*128 + wc*64 + n*16 + lr)*8]);
#pragma unroll
        for (int m = 0; m < 4; ++m)
#pragma unroll
            for (int n = 0; n < 4; ++n)
                acc[m][n] = __builtin_amdgcn_mfma_f32_16x16x32_bf16(af[m], bfv[n], acc[m][n], 0, 0, 0);
        if (kt + 1 < KDIM / 32) regs_to_lds(buf ^ 1);
        buf ^= 1;
    }
#pragma unroll
    for (int m = 0; m < 4; ++m) {
        const int row0 = bm + wr * 64 + m * 16 + lq * 4;
#pragma unroll
        for (int n = 0; n < 4; ++n) {
            const int col = bn + wc * 64 + n * 16 + lr;
#pragma unroll
            for (int j = 0; j < 4; ++j)
                Ob[(size_t)(row0 + j) * NDIM + col] = acc[m][n][j];
        }
    }
}

extern "C" void kernel_launch(void* const* d_in, const int* in_sizes, int n_in,
                              void* d_out, int out_size, void* d_ws, size_t ws_size,
                              hipStream_t stream) {
    const float* a = (const float*)d_in[0];
    const float* b = (const float*)d_in[1];
    float* o = (float*)d_out;
    const size_t half = (size_t)BATCH * SDIM * KDIM * sizeof(bf16_t);  // 64 MiB
    if (ws_size >= 2 * half) {
        bf16_t* Abf = (bf16_t*)d_ws;
        bf16_t* Bt = (bf16_t*)((char*)d_ws + half);
        hipLaunchKernelGGL(cvtA_kernel, dim3(4096), dim3(256), 0, stream, a, Abf);
        hipLaunchKernelGGL(cvtBT_kernel, dim3(8192), dim3(256), 0, stream, b, Bt);
        hipLaunchKernelGGL(bgemm_m201, dim3(512), dim3(512), 0, stream, Abf, Bt, o);
    } else {
        hipLaunchKernelGGL(bgemm_fused, dim3(2048), dim3(256), 0, stream, a, b, o);
    }
}

// Round 15
// 233.608 us; speedup vs baseline: 1.2929x; 1.0781x over previous
//
#include <hip/hip_runtime.h>

#define BATCH 8
#define SDIM 2048
#define KDIM 2048
#define NDIM 2048
#define BK 32
#define NKT (KDIM / BK)   // 64

typedef __bf16 bf16_t;
typedef bf16_t bf16x8 __attribute__((ext_vector_type(8)));
typedef float f32x4 __attribute__((ext_vector_type(4)));

// ---- Fused fp32->bf16 batched GEMM, 256x256 tile, 8 waves (2M x 4N) ----
// Eliminates the separate conversion passes (they were 70us of pure HBM BW).
// Staging is reg-based: fp32 global loads -> cvt -> ds_write (bf16). Plain
// HIP loads everywhere: the compiler inserts precisely-counted vmcnt before
// the cvt uses (loads for tile j+2 are issued a full K-tile before use) and
// counted lgkmcnt between ds_read and MFMA. Exactly ONE explicit
// lgkmcnt(0)+s_barrier per K-tile:
//   iter j (buf p = j&1):
//     frag reads(j) from buf p       12 ds_read_b128 (conflict-free layout)
//     MFMA(j)                        32 mfma_16x16x32
//     CVT+WRITE tile j+1 -> buf p^1  (regs loaded at iter j-1; WAR vs other
//                                     waves' reads(j-1) certified by the
//                                     lgkm0+BAR at end of iter j-1)
//     LOAD tile j+2 -> regs          (plain loads, land during iter j+1)
//     lgkm0; s_barrier               (writes visible + everyone's reads(j) done)
// LDS layouts (R1-verified, 0 bank conflicts measured):
//   A: [buf][kOct 0..3][row 0..255][8 bf16]  (16KB/buf)  B: same over cols.
//   Staging writes: lanes 0-31 write 32x16B contiguous per kOct. Fragment
//   reads: 16-lane groups read 256B contiguous.
__global__ __launch_bounds__(512, 2)
void bgemm_fcvt(const float* __restrict__ A, const float* __restrict__ B,
                float* __restrict__ O) {
    __shared__ alignas(16) bf16_t Asl[2][4 * 256 * 8];   // 2 x 16 KB
    __shared__ alignas(16) bf16_t Bsl[2][4 * 256 * 8];   // 2 x 16 KB

    const int tid = threadIdx.x;
    const int gid = blockIdx.x;
    const int batch = gid & 7;          // one batch per XCD (512 = 8*64, bijective)
    const int t = gid >> 3;             // 0..63
    const int bm = (t >> 3) * 256;
    const int bn = (t & 7) * 256;

    const int lane = tid & 63;
    const int wid = tid >> 6;           // 0..7
    const int wr = wid >> 2;            // 0..1 (128-row half)
    const int wc = wid & 3;             // 0..3 (64-col quarter)
    const int lr = lane & 15;
    const int lq = lane >> 4;

    const float* Ab = A + (size_t)batch * SDIM * KDIM;
    const float* Bb = B + (size_t)batch * KDIM * NDIM;
    float* Ob = O + (size_t)batch * SDIM * NDIM;

    // staging roles: wave w covers A rows / B cols [w*32, w*32+32);
    // lane&31 -> row/col within group, lane>>5 -> which 16-wide k-half
    const int sr = wid * 32 + (lane & 31);
    const int sh = lane >> 5;
    const float* aP = Ab + (size_t)(bm + sr) * KDIM + sh * 16;
    const float* bP = Bb + (size_t)(sh * 16) * NDIM + bn + sr;

    f32x4 rA[4];      // 16 fp32, k-contiguous for row sr
    float rB[16];     // 16 fp32, k-strided for col sr (all indices static)

#define LOADT(KT_) do { \
    const float* ap_ = aP + (size_t)(KT_) * BK; \
    rA[0] = *reinterpret_cast<const f32x4*>(ap_); \
    rA[1] = *reinterpret_cast<const f32x4*>(ap_ + 4); \
    rA[2] = *reinterpret_cast<const f32x4*>(ap_ + 8); \
    rA[3] = *reinterpret_cast<const f32x4*>(ap_ + 12); \
    const float* bp_ = bP + (size_t)(KT_) * BK * NDIM; \
    _Pragma("unroll") \
    for (int i_ = 0; i_ < 16; ++i_) rB[i_] = bp_[(size_t)i_ * NDIM]; \
} while (0)

#define CVTWR(P_) do { \
    bf16x8 w0_, w1_; \
    _Pragma("unroll") \
    for (int i_ = 0; i_ < 4; ++i_) { \
        w0_[i_] = (bf16_t)rA[0][i_]; w0_[4 + i_] = (bf16_t)rA[1][i_]; \
        w1_[i_] = (bf16_t)rA[2][i_]; w1_[4 + i_] = (bf16_t)rA[3][i_]; \
    } \
    *reinterpret_cast<bf16x8*>(&Asl[P_][((sh * 2 + 0) * 256 + sr) * 8]) = w0_; \
    *reinterpret_cast<bf16x8*>(&Asl[P_][((sh * 2 + 1) * 256 + sr) * 8]) = w1_; \
    _Pragma("unroll") \
    for (int i_ = 0; i_ < 8; ++i_) { \
        w0_[i_] = (bf16_t)rB[i_]; w1_[i_] = (bf16_t)rB[8 + i_]; \
    } \
    *reinterpret_cast<bf16x8*>(&Bsl[P_][((sh * 2 + 0) * 256 + sr) * 8]) = w0_; \
    *reinterpret_cast<bf16x8*>(&Bsl[P_][((sh * 2 + 1) * 256 + sr) * 8]) = w1_; \
} while (0)

    f32x4 acc[8][4];
#pragma unroll
    for (int m = 0; m < 8; ++m)
#pragma unroll
        for (int n = 0; n < 4; ++n)
            acc[m][n] = (f32x4){0.f, 0.f, 0.f, 0.f};

#define ITER(P_, J_, DOLOAD_, DOWRITE_) do { \
    bf16x8 af_[8], bf_[4]; \
    _Pragma("unroll") \
    for (int m_ = 0; m_ < 8; ++m_) \
        af_[m_] = *reinterpret_cast<const bf16x8*>( \
            &Asl[P_][(lq * 256 + wr * 128 + m_ * 16 + lr) * 8]); \
    _Pragma("unroll") \
    for (int n_ = 0; n_ < 4; ++n_) \
        bf_[n_] = *reinterpret_cast<const bf16x8*>( \
            &Bsl[P_][(lq * 256 + wc * 64 + n_ * 16 + lr) * 8]); \
    _Pragma("unroll") \
    for (int m_ = 0; m_ < 8; ++m_) \
        _Pragma("unroll") \
        for (int n_ = 0; n_ < 4; ++n_) \
            acc[m_][n_] = __builtin_amdgcn_mfma_f32_16x16x32_bf16( \
                af_[m_], bf_[n_], acc[m_][n_], 0, 0, 0); \
    if (DOWRITE_) CVTWR((P_) ^ 1);            /* tile J_+1 (regs from iter J_-1) */ \
    if (DOLOAD_) LOADT((J_) + 2);             /* lands during iter J_+1 */ \
    asm volatile("s_waitcnt lgkmcnt(0)" ::: "memory"); \
    __builtin_amdgcn_s_barrier(); \
} while (0)

    // prologue: tile0 -> buf0; tile1 loads in flight
    LOADT(0);
    CVTWR(0);
    LOADT(1);
    asm volatile("s_waitcnt lgkmcnt(0)" ::: "memory");
    __builtin_amdgcn_s_barrier();

#pragma unroll 1
    for (int j = 0; j < 62; j += 2) {
        ITER(0, j, 1, 1);
        ITER(1, j + 1, 1, 1);
    }
    ITER(0, 62, 0, 1);    // writes tile 63 (loaded at j=61), no more loads
    ITER(1, 63, 0, 0);    // pure compute

    // epilogue: C/D layout col=lane&15, row=(lane>>4)*4+reg (R1-verified)
#pragma unroll
    for (int m = 0; m < 8; ++m) {
        const int row0 = bm + wr * 128 + m * 16 + lq * 4;
#pragma unroll
        for (int n = 0; n < 4; ++n) {
            const int col = bn + wc * 64 + n * 16 + lr;
#pragma unroll
            for (int j = 0; j < 4; ++j)
                Ob[(size_t)(row0 + j) * NDIM + col] = acc[m][n][j];
        }
    }
#undef ITER
#undef CVTWR
#undef LOADT
}

extern "C" void kernel_launch(void* const* d_in, const int* in_sizes, int n_in,
                              void* d_out, int out_size, void* d_ws, size_t ws_size,
                              hipStream_t stream) {
    const float* a = (const float*)d_in[0];
    const float* b = (const float*)d_in[1];
    float* o = (float*)d_out;
    // 8 batches x (2048/256) x (2048/256) = 512 blocks, one batch per XCD
    hipLaunchKernelGGL(bgemm_fcvt, dim3(512), dim3(512), 0, stream, a, b, o);
}